// Round 14
// baseline (1458.791 us; speedup 1.0000x reference)
//
#include <hip/hip_runtime.h>
#include <hip/hip_fp16.h>
#include <math.h>

#define BB 512
#define NN 64
#define KNB 16
#define NPTS (BB*NN)        // 32768
#define NEDGE (BB*NN*KNB)   // 524288
#define EPSV 1e-5f

typedef __attribute__((ext_vector_type(8))) _Float16 f16x8;
typedef __attribute__((ext_vector_type(4))) _Float16 f16x4;
typedef __attribute__((ext_vector_type(4))) float f32x4;

__device__ __forceinline__ float lrelu(float x){ return x > 0.0f ? x : 0.2f*x; }
__device__ __forceinline__ unsigned encf(float f){
    unsigned u = __float_as_uint(f);
    return (u & 0x80000000u) ? ~u : (u | 0x80000000u);
}
__device__ __forceinline__ float decf(unsigned e){
    unsigned u = (e & 0x80000000u) ? (e ^ 0x80000000u) : ~e;
    return __uint_as_float(u);
}
#define ENC_NEGINF 0x007FFFFFu   // encf(-inf)

// scaled 2-plane f16 split: v = h + (m/2048); both planes normal-range f16.
__device__ __forceinline__ void split2h(float v, _Float16& h, _Float16& m){
    h = (_Float16)v;
    float r = v - (float)h;
    m = (_Float16)(r * 2048.0f);
}

// ---------------- input MLP ----------------
__global__ void k_input(const float* __restrict__ x, const float* __restrict__ w,
                        float* __restrict__ h0){
    __shared__ float wls[6*64];
    int t = threadIdx.x;
    for (int i = t; i < 6*64; i += 256) wls[i] = w[i];
    __syncthreads();
    int row = blockIdx.x*256 + t;
    float xv[6];
#pragma unroll
    for (int k = 0; k < 6; k++) xv[k] = x[row*6 + k];
#pragma unroll 8
    for (int c = 0; c < 64; c++){
        float acc = 0.f;
#pragma unroll
        for (int k = 0; k < 6; k++) acc += xv[k]*wls[k*64 + c];
        h0[(size_t)row*64 + c] = acc;
    }
}

// ---- column stats, deterministic partials ----
__global__ void k_colstats_part(const float* __restrict__ h,
                                float* __restrict__ pS, float* __restrict__ pQ){
    int t = threadIdx.x;
    int c = t & 63;
    int g = t >> 6;
    int p = blockIdx.x*4 + g;
    const int rpb = NPTS/256;
    int r0 = p*rpb;
    float s = 0.f, q = 0.f;
    for (int r = r0; r < r0 + rpb; r++){
        float v = h[(size_t)r*64 + c];
        s += v; q += v*v;
    }
    pS[c*256 + p] = s;
    pQ[c*256 + p] = q;
}

// ---- BN finalize from partials (deterministic serial reduce) ----
__global__ void k_bnfin_part(const float* __restrict__ pS, const float* __restrict__ pQ,
                             const float* __restrict__ g, const float* __restrict__ b,
                             float* __restrict__ cA, float* __restrict__ cB,
                             int P, float invM){
    int c = threadIdx.x;
    const float* ps = pS + (size_t)c*P;
    const float* pq = pQ + (size_t)c*P;
    float s = 0.f, q = 0.f;
    for (int p = 0; p < P; p += 4){
        float4 vs = *(const float4*)(ps + p);
        float4 vq = *(const float4*)(pq + p);
        s += vs.x + vs.y + vs.z + vs.w;
        q += vq.x + vq.y + vq.z + vq.w;
    }
    float m = s*invM;
    float v = q*invM - m*m;
    v = v < 0.f ? 0.f : v;
    float a = g[c]*rsqrtf(v + EPSV);
    cA[c] = a;
    cB[c] = b[c] - m*a;
}

// ---------------- BN finalize from atomic sums (classifier only) ----------------
__global__ void k_bnfin(const float* gs, const float* gq, const float* g,
                        const float* b, float* cA, float* cB, int C, float invM){
    int c = blockIdx.x*blockDim.x + threadIdx.x;
    if (c < C){
        float m = gs[c]*invM;
        float v = gq[c]*invM - m*m;
        v = v < 0.f ? 0.f : v;
        float a = g[c]*rsqrtf(v + EPSV);
        cA[c] = a;
        cB[c] = b[c] - m*a;
    }
}

// ---------------- in-place bn+lrelu apply ----------------
__global__ void k_apply(float* h, const float* __restrict__ cA,
                        const float* __restrict__ cB, int C, int total){
    int i = blockIdx.x*256 + threadIdx.x;
    if (i < total){
        int c = i & (C-1);
        h[i] = lrelu(cA[c]*h[i] + cB[c]);
    }
}

// ---- pqfold: fold BN coefs into f16 P,Q in place (stage 3):
//  P' = cA*P + cB ; Q' = cA*Q  -> mm2 act = lrelu(P'[n] + Q'[j])
__global__ void k_pqfold(_Float16* __restrict__ P, _Float16* __restrict__ Q,
                         const float* __restrict__ cA, const float* __restrict__ cB){
    int i = (blockIdx.x*256 + threadIdx.x)*8;      // over NPTS*256
    int k = i & 255;
    f16x8 ca, cb;
#pragma unroll
    for (int u = 0; u < 8; u++){ ca[u] = (_Float16)cA[k+u]; cb[u] = (_Float16)cB[k+u]; }
    f16x8 p = *(const f16x8*)(P + i);
    f16x8 q = *(const f16x8*)(Q + i);
    *(f16x8*)(P + i) = ca*p + cb;
    *(f16x8*)(Q + i) = ca*q;
}

// ---------------- knn: ILP-blocked distances + bitonic-sort selection ----------
template<int C>
__global__ void k_knn(const float* __restrict__ x, int* __restrict__ idxg){
    const int CP = C + 4;
    __shared__ __align__(16) float xls[64*CP];
    __shared__ float sq[64];
    __shared__ __align__(16) float dls[64*64];
    int t = threadIdx.x, b = blockIdx.x;
    const float* xb = x + (size_t)b*64*C;
    for (int i = t; i < 64*C; i += 256){
        int n = i / C, c = i & (C-1);
        xls[n*CP + c] = xb[i];
    }
    __syncthreads();
    if (t < 64){
        float s = 0.f;
        for (int c = 0; c < C; c += 4){
            float4 v = *(const float4*)&xls[t*CP + c];
            s += v.x*v.x + v.y*v.y + v.z*v.z + v.w*v.w;
        }
        sq[t] = s;
    }
    __syncthreads();
    {
        int n  = t >> 2;
        int m0 = (t & 3)*16;
        float acc[16];
#pragma unroll
        for (int i = 0; i < 16; i++) acc[i] = 0.f;
        const float* an = &xls[n*CP];
        const float* bm = &xls[m0*CP];
        for (int c = 0; c < C; c += 4){
            float4 a = *(const float4*)(an + c);
#pragma unroll
            for (int i = 0; i < 16; i++){
                float4 bv = *(const float4*)(bm + i*CP + c);
                acc[i] += a.x*bv.x + a.y*bv.y + a.z*bv.z + a.w*bv.w;
            }
        }
        float sn = sq[n];
#pragma unroll
        for (int i4 = 0; i4 < 16; i4 += 4){
            float4 dv;
            dv.x = sn - 2.0f*acc[i4+0] + sq[m0+i4+0];
            dv.y = sn - 2.0f*acc[i4+1] + sq[m0+i4+1];
            dv.z = sn - 2.0f*acc[i4+2] + sq[m0+i4+2];
            dv.w = sn - 2.0f*acc[i4+3] + sq[m0+i4+3];
            *(float4*)&dls[n*64 + m0 + i4] = dv;
        }
    }
    __syncthreads();
    int lane = t & 63, w = t >> 6;
    for (int pr = 0; pr < 16; pr += 4){
        int n0 = w*16 + pr;
        unsigned long long c0 = (((unsigned long long)encf(dls[(n0+0)*64 + lane])) << 32) | (unsigned)lane;
        unsigned long long c1 = (((unsigned long long)encf(dls[(n0+1)*64 + lane])) << 32) | (unsigned)lane;
        unsigned long long c2 = (((unsigned long long)encf(dls[(n0+2)*64 + lane])) << 32) | (unsigned)lane;
        unsigned long long c3 = (((unsigned long long)encf(dls[(n0+3)*64 + lane])) << 32) | (unsigned)lane;
#pragma unroll
        for (int k = 2; k <= 64; k <<= 1){
#pragma unroll
            for (int j = k >> 1; j > 0; j >>= 1){
                bool keepmin = ((lane & j) == 0) == ((lane & k) == 0);
                unsigned long long o0 = __shfl_xor(c0, j, 64);
                unsigned long long o1 = __shfl_xor(c1, j, 64);
                unsigned long long o2 = __shfl_xor(c2, j, 64);
                unsigned long long o3 = __shfl_xor(c3, j, 64);
                c0 = keepmin ? (c0 < o0 ? c0 : o0) : (c0 < o0 ? o0 : c0);
                c1 = keepmin ? (c1 < o1 ? c1 : o1) : (c1 < o1 ? o1 : c1);
                c2 = keepmin ? (c2 < o2 ? c2 : o2) : (c2 < o2 ? o2 : c2);
                c3 = keepmin ? (c3 < o3 ? c3 : o3) : (c3 < o3 ? o3 : c3);
            }
        }
        if (lane >= 1 && lane <= KNB){
            int base = b*1024 + n0*16 + lane - 1;
            idxg[base]      = (int)(c0 & 0xffffffffu);
            idxg[base + 16] = (int)(c1 & 0xffffffffu);
            idxg[base + 32] = (int)(c2 & 0xffffffffu);
            idxg[base + 48] = (int)(c3 & 0xffffffffu);
        }
    }
}

// ---- weight prep: wb = w1[CIN+k][c], wd = w1[k][c]-wb -> transposed f16 planes
template<int CIN, int CMID, bool SPLIT>
__global__ void k_wprep(const float* __restrict__ w1,
                        _Float16* __restrict__ wbh, _Float16* __restrict__ wbm,
                        _Float16* __restrict__ wdh, _Float16* __restrict__ wdm){
    int i = blockIdx.x*256 + threadIdx.x;
    if (i >= CIN*CMID) return;
    int k = i / CMID, c = i - k*CMID;
    float wb = w1[(size_t)(CIN + k)*CMID + c];
    float wd = w1[(size_t)k*CMID + c] - wb;
    size_t o = (size_t)c*CIN + k;
    if (SPLIT){
        _Float16 h, m;
        split2h(wb, h, m); wbh[o] = h; wbm[o] = m;
        split2h(wd, h, m); wdh[o] = h; wdm[o] = m;
    } else {
        wbh[o] = (_Float16)wb;
        wdh[o] = (_Float16)wd;
    }
}

// ---- mm1x: P = x@wb, Q = x@wd via split2h f16 MFMA (stages 1,2; f32 out) ----
template<int CIN, int CMID>
__global__ __launch_bounds__(256)
void k_mm1x(const float* __restrict__ x,
            const _Float16* __restrict__ wbh, const _Float16* __restrict__ wbm,
            const _Float16* __restrict__ wdh, const _Float16* __restrict__ wdm,
            float* __restrict__ P, float* __restrict__ Q){
    int t = threadIdx.x, b = blockIdx.x;
    int lane = t & 63, w = t >> 6;
    int lrow = lane & 15, lk = lane >> 4;
    const int KT = CIN/32;
    f16x8 ah[KT], am[KT];
    {
        const float* xr = x + ((size_t)b*64 + w*16 + lrow)*CIN;
#pragma unroll
        for (int kt = 0; kt < KT; kt++){
            union { f16x8 v; _Float16 u[8]; } H, M;
#pragma unroll
            for (int j = 0; j < 8; j++)
                split2h(xr[kt*32 + lk*8 + j], H.u[j], M.u[j]);
            ah[kt] = H.v; am[kt] = M.v;
        }
    }
#pragma unroll
    for (int ct = 0; ct < CMID/16; ct++){
        int col = ct*16 + lrow;
        f32x4 aPM = {0,0,0,0}, aPC = {0,0,0,0};
        f32x4 aQM = {0,0,0,0}, aQC = {0,0,0,0};
#pragma unroll
        for (int kt = 0; kt < KT; kt++){
            size_t bo = (size_t)col*CIN + kt*32 + lk*8;
            f16x8 bbh = *(const f16x8*)(wbh + bo);
            f16x8 bbm = *(const f16x8*)(wbm + bo);
            f16x8 bdh = *(const f16x8*)(wdh + bo);
            f16x8 bdm = *(const f16x8*)(wdm + bo);
            aPM = __builtin_amdgcn_mfma_f32_16x16x32_f16(ah[kt], bbh, aPM, 0, 0, 0);
            aPC = __builtin_amdgcn_mfma_f32_16x16x32_f16(ah[kt], bbm, aPC, 0, 0, 0);
            aPC = __builtin_amdgcn_mfma_f32_16x16x32_f16(am[kt], bbh, aPC, 0, 0, 0);
            aQM = __builtin_amdgcn_mfma_f32_16x16x32_f16(ah[kt], bdh, aQM, 0, 0, 0);
            aQC = __builtin_amdgcn_mfma_f32_16x16x32_f16(ah[kt], bdm, aQC, 0, 0, 0);
            aQC = __builtin_amdgcn_mfma_f32_16x16x32_f16(am[kt], bdh, aQC, 0, 0, 0);
        }
#pragma unroll
        for (int u = 0; u < 4; u++){
            size_t o = ((size_t)b*64 + w*16 + lk*4 + u)*CMID + col;
            P[o] = aPM[u] + aPC[u]*(1.0f/2048.0f);
            Q[o] = aQM[u] + aQC[u]*(1.0f/2048.0f);
        }
    }
}

// ---- mm1xh: stage 3, plain f16 MFMA, f16 outputs ----
template<int CIN, int CMID>
__global__ __launch_bounds__(256)
void k_mm1xh(const float* __restrict__ x,
             const _Float16* __restrict__ wbh, const _Float16* __restrict__ wdh,
             _Float16* __restrict__ P, _Float16* __restrict__ Q){
    int t = threadIdx.x, b = blockIdx.x;
    int lane = t & 63, w = t >> 6;
    int lrow = lane & 15, lk = lane >> 4;
    const int KT = CIN/32;
    f16x8 ah[KT];
    {
        const float* xr = x + ((size_t)b*64 + w*16 + lrow)*CIN;
#pragma unroll
        for (int kt = 0; kt < KT; kt++){
            union { f16x8 v; _Float16 u[8]; } H;
#pragma unroll
            for (int j = 0; j < 8; j++)
                H.u[j] = (_Float16)xr[kt*32 + lk*8 + j];
            ah[kt] = H.v;
        }
    }
#pragma unroll
    for (int ct = 0; ct < CMID/16; ct++){
        int col = ct*16 + lrow;
        f32x4 aP = {0,0,0,0}, aQ = {0,0,0,0};
#pragma unroll
        for (int kt = 0; kt < KT; kt++){
            size_t bo = (size_t)col*CIN + kt*32 + lk*8;
            f16x8 bbh = *(const f16x8*)(wbh + bo);
            f16x8 bdh = *(const f16x8*)(wdh + bo);
            aP = __builtin_amdgcn_mfma_f32_16x16x32_f16(ah[kt], bbh, aP, 0, 0, 0);
            aQ = __builtin_amdgcn_mfma_f32_16x16x32_f16(ah[kt], bdh, aQ, 0, 0, 0);
        }
#pragma unroll
        for (int u = 0; u < 4; u++){
            size_t o = ((size_t)b*64 + w*16 + lk*4 + u)*CMID + col;
            P[o] = (_Float16)aP[u];
            Q[o] = (_Float16)aQ[u];
        }
    }
}

// ---- stats over per-edge h = P[n]+Q[idx], f32 inputs (stages 1,2) ----
template<int CMID>
__global__ void k_stats1p(const float* __restrict__ P, const float* __restrict__ Q,
                          const int* __restrict__ idxg,
                          float* __restrict__ pS, float* __restrict__ pQ){
    int t = threadIdx.x, b = blockIdx.x;
    const int NG = 256/CMID;
    const int PT = 512*NG;
    int c = t & (CMID-1);
    int g = t / CMID;
    int epg = 1024/NG;
    const float* Pb = P + (size_t)b*64*CMID;
    const float* Qb = Q + (size_t)b*64*CMID;
    const int* ib = idxg + b*1024;
    float s = 0.f, q = 0.f;
    for (int e = g*epg; e < (g+1)*epg; e++){
        int n = e >> 4;
        int j = ib[e];
        float v = Pb[n*CMID + c] + Qb[j*CMID + c];
        s += v; q += v*v;
    }
    int p = b*NG + g;
    pS[(size_t)c*PT + p] = s;
    pQ[(size_t)c*PT + p] = q;
}

// ---- stats1h: f16 inputs, P-row hoisted (stage 3); fixed summation order ----
__global__ void k_stats1h(const _Float16* __restrict__ P, const _Float16* __restrict__ Q,
                          const int* __restrict__ idxg,
                          float* __restrict__ pS, float* __restrict__ pQ){
    __shared__ int ils[1024];
    int t = threadIdx.x, b = blockIdx.x;
    for (int i = t; i < 1024; i += 256) ils[i] = idxg[b*1024 + i];
    __syncthreads();
    const _Float16* Pb = P + (size_t)b*64*256;
    const _Float16* Qb = Q + (size_t)b*64*256;
    float s = 0.f, q = 0.f;
    for (int n = 0; n < 64; n++){
        float p = (float)Pb[n*256 + t];
#pragma unroll 4
        for (int k = 0; k < 16; k++){
            int j = ils[n*16 + k];
            float v = p + (float)Qb[j*256 + t];
            s += v; q += v*v;
        }
    }
    pS[(size_t)t*512 + b] = s;
    pQ[(size_t)t*512 + b] = q;
}

// ---------------- mm2s: scaled 2-plane f16 MFMA (stages 1,2 — feed knn) --------
template<int CMID, int COUT, int NSET>
__global__ __launch_bounds__(256, 3)
void k_mm2s(const float* __restrict__ P, const float* __restrict__ Q,
            const int* __restrict__ idxg,
            const float* __restrict__ cA1, const float* __restrict__ cB1,
            const float* __restrict__ w2, const float* __restrict__ g2,
            unsigned* __restrict__ outenc,
            float* __restrict__ pS, float* __restrict__ pQ){
    const int AS = CMID + 8;
    const int NCOL = 64*NSET;
    __shared__ __align__(16) _Float16 act_h[32*AS];
    __shared__ __align__(16) _Float16 act_m[32*AS];
    __shared__ unsigned maxtab[NCOL*64];
    __shared__ unsigned short ils[1024];
    __shared__ __align__(16) float a1ls[CMID];
    __shared__ __align__(16) float b1ls[CMID];
    int t = threadIdx.x, b = blockIdx.x, cc = blockIdx.y;
    int lane = t & 63, w = t >> 6;
    int lrow = lane & 15, lk = lane >> 4;

    for (int i = t; i < 1024; i += 256) ils[i] = (unsigned short)idxg[b*1024 + i];
    for (int i = t; i < CMID; i += 256){ a1ls[i] = cA1[i]; b1ls[i] = cB1[i]; }
    for (int i = t; i < NCOL*64; i += 256) maxtab[i] = ENC_NEGINF;

    const int KT = CMID/32;
    f16x8 bh[NSET][KT], bm[NSET][KT];
    float sg[NSET];
    int ccBase = cc*NCOL;
#pragma unroll
    for (int s = 0; s < NSET; s++){
        int ncol = ccBase + s*64 + w*16 + lrow;
#pragma unroll
        for (int kt = 0; kt < KT; kt++){
            union { f16x8 v; _Float16 u[8]; } uh, um;
#pragma unroll
            for (int j = 0; j < 8; j++){
                int k = kt*32 + lk*8 + j;
                split2h(w2[(size_t)k*COUT + ncol], uh.u[j], um.u[j]);
            }
            bh[s][kt] = uh.v; bm[s][kt] = um.v;
        }
        sg[s] = (g2[ncol] < 0.0f) ? -1.0f : 1.0f;
    }
    float ss[NSET], qq[NSET];
#pragma unroll
    for (int s = 0; s < NSET; s++){ ss[s] = 0.f; qq[s] = 0.f; }
    const float* Pb = P + (size_t)b*64*CMID;
    const float* Qb = Q + (size_t)b*64*CMID;
    __syncthreads();

    for (int ch = 0; ch < 32; ch++){
        for (int i = t*4; i < 32*CMID; i += 1024){
            int le = i / CMID, k = i & (CMID-1);
            int e = ch*32 + le;
            int n = e >> 4, j = ils[e];
            float4 pv = *(const float4*)(Pb + n*CMID + k);
            float4 qv = *(const float4*)(Qb + j*CMID + k);
            float4 ca = *(const float4*)&a1ls[k];
            float4 cb = *(const float4*)&b1ls[k];
            float v0 = lrelu(ca.x*(pv.x + qv.x) + cb.x);
            float v1 = lrelu(ca.y*(pv.y + qv.y) + cb.y);
            float v2 = lrelu(ca.z*(pv.z + qv.z) + cb.z);
            float v3 = lrelu(ca.w*(pv.w + qv.w) + cb.w);
            union { f16x4 v; _Float16 u[4]; } hh, mm;
            split2h(v0, hh.u[0], mm.u[0]);
            split2h(v1, hh.u[1], mm.u[1]);
            split2h(v2, hh.u[2], mm.u[2]);
            split2h(v3, hh.u[3], mm.u[3]);
            *(f16x4*)&act_h[le*AS + k] = hh.v;
            *(f16x4*)&act_m[le*AS + k] = mm.v;
        }
        __syncthreads();

        f32x4 accM[2][NSET], accC[2][NSET];
#pragma unroll
        for (int r = 0; r < 2; r++)
#pragma unroll
            for (int s = 0; s < NSET; s++){
                accM[r][s] = {0.f,0.f,0.f,0.f};
                accC[r][s] = {0.f,0.f,0.f,0.f};
            }
#pragma unroll
        for (int kt = 0; kt < KT; kt++){
            int ko = kt*32 + lk*8;
#pragma unroll
            for (int r = 0; r < 2; r++){
                f16x8 ah = *(const f16x8*)&act_h[(r*16 + lrow)*AS + ko];
                f16x8 am = *(const f16x8*)&act_m[(r*16 + lrow)*AS + ko];
#pragma unroll
                for (int s = 0; s < NSET; s++){
                    accM[r][s] = __builtin_amdgcn_mfma_f32_16x16x32_f16(ah, bh[s][kt], accM[r][s], 0, 0, 0);
                    accC[r][s] = __builtin_amdgcn_mfma_f32_16x16x32_f16(ah, bm[s][kt], accC[r][s], 0, 0, 0);
                    accC[r][s] = __builtin_amdgcn_mfma_f32_16x16x32_f16(am, bh[s][kt], accC[r][s], 0, 0, 0);
                }
            }
        }
#pragma unroll
        for (int r = 0; r < 2; r++){
#pragma unroll
            for (int s = 0; s < NSET; s++){
                int colL = s*64 + w*16 + lrow;
#pragma unroll
                for (int u = 0; u < 4; u++){
                    int e = ch*32 + r*16 + lk*4 + u;
                    float v = accM[r][s][u] + accC[r][s][u]*(1.0f/2048.0f);
                    ss[s] += v; qq[s] += v*v;
                    int j = ils[e];
                    atomicMax(&maxtab[colL*64 + (j ^ (colL & 31))], encf(sg[s]*v));
                }
            }
        }
        __syncthreads();
    }
#pragma unroll
    for (int s = 0; s < NSET; s++){
        ss[s] += __shfl_xor(ss[s], 16, 64); ss[s] += __shfl_xor(ss[s], 32, 64);
        qq[s] += __shfl_xor(qq[s], 16, 64); qq[s] += __shfl_xor(qq[s], 32, 64);
        if (lane < 16){
            pS[(size_t)(ccBase + s*64 + w*16 + lane)*512 + b] = ss[s];
            pQ[(size_t)(ccBase + s*64 + w*16 + lane)*512 + b] = qq[s];
        }
    }
    for (int i = t; i < 64*NCOL; i += 256){
        int colL = i % NCOL, j = i / NCOL;
        outenc[((size_t)b*64 + j)*COUT + ccBase + colL] = maxtab[colL*64 + (j ^ (colL & 31))];
    }
}

// ---------------- mm2xh: register-streamed f16 MFMA (stage 3) ------------------
// act built per-wave in registers from BN-folded P',Q' (k_pqfold); no LDS act,
// 2 barriers total. A-row n = 2ch+r is wave-uniform; Q rows L2-hot.
template<int CMID, int COUT, int NSET>
__global__ __launch_bounds__(256)
void k_mm2xh(const _Float16* __restrict__ P, const _Float16* __restrict__ Q,
             const int* __restrict__ idxg,
             const float* __restrict__ w2, const float* __restrict__ g2,
             unsigned* __restrict__ outenc,
             float* __restrict__ pS, float* __restrict__ pQ){
    const int NCOL = 64*NSET;
    __shared__ unsigned maxtab[NCOL*64];
    __shared__ unsigned short ils[1024];
    int t = threadIdx.x, b = blockIdx.x, cc = blockIdx.y;
    int lane = t & 63, w = t >> 6;
    int lrow = lane & 15, lk = lane >> 4;

    for (int i = t; i < 1024; i += 256) ils[i] = (unsigned short)idxg[b*1024 + i];
    for (int i = t; i < NCOL*64; i += 256) maxtab[i] = ENC_NEGINF;

    const int KT = CMID/32;
    f16x8 breg[NSET][KT];
    float sg[NSET];
    int ccBase = cc*NCOL;
#pragma unroll
    for (int s = 0; s < NSET; s++){
        int ncol = ccBase + s*64 + w*16 + lrow;
#pragma unroll
        for (int kt = 0; kt < KT; kt++){
            union { f16x8 v; _Float16 u[8]; } bu;
#pragma unroll
            for (int j = 0; j < 8; j++){
                int k = kt*32 + lk*8 + j;
                bu.u[j] = (_Float16)w2[(size_t)k*COUT + ncol];
            }
            breg[s][kt] = bu.v;
        }
        sg[s] = (g2[ncol] < 0.0f) ? -1.0f : 1.0f;
    }
    float ss[NSET], qq[NSET];
#pragma unroll
    for (int s = 0; s < NSET; s++){ ss[s] = 0.f; qq[s] = 0.f; }
    const _Float16* Pb = P + (size_t)b*64*CMID;
    const _Float16* Qb = Q + (size_t)b*64*CMID;
    __syncthreads();   // ils + maxtab ready

    for (int ch = 0; ch < 32; ch++){
        f32x4 acc[2][NSET];
#pragma unroll
        for (int r = 0; r < 2; r++)
#pragma unroll
            for (int s = 0; s < NSET; s++) acc[r][s] = {0.f,0.f,0.f,0.f};
#pragma unroll
        for (int r = 0; r < 2; r++){
            int n = ch*2 + r;                       // e>>4, lrow<16
            int j = ils[ch*32 + r*16 + lrow];
            const _Float16* Pr = Pb + (size_t)n*CMID;
            const _Float16* Qr = Qb + (size_t)j*CMID;
#pragma unroll
            for (int kt = 0; kt < KT; kt++){
                int ko = kt*32 + lk*8;
                f16x8 p = *(const f16x8*)(Pr + ko);
                f16x8 q = *(const f16x8*)(Qr + ko);
                f16x8 v = p + q;
                f16x8 vm = v * (_Float16)0.2f;
                union { f16x8 x; _Float16 e8[8]; } V, M, R;
                V.x = v; M.x = vm;
#pragma unroll
                for (int u = 0; u < 8; u++)
                    R.e8[u] = (V.e8[u] > (_Float16)0.0f) ? V.e8[u] : M.e8[u];
#pragma unroll
                for (int s = 0; s < NSET; s++)
                    acc[r][s] = __builtin_amdgcn_mfma_f32_16x16x32_f16(R.x, breg[s][kt], acc[r][s], 0, 0, 0);
            }
        }
#pragma unroll
        for (int r = 0; r < 2; r++){
#pragma unroll
            for (int s = 0; s < NSET; s++){
                int colL = s*64 + w*16 + lrow;
#pragma unroll
                for (int u = 0; u < 4; u++){
                    int e = ch*32 + r*16 + lk*4 + u;
                    float v = acc[r][s][u];
                    ss[s] += v; qq[s] += v*v;
                    int j = ils[e];
                    atomicMax(&maxtab[colL*64 + (j ^ (colL & 31))], encf(sg[s]*v));
                }
            }
        }
    }
    __syncthreads();   // all atomics done
#pragma unroll
    for (int s = 0; s < NSET; s++){
        ss[s] += __shfl_xor(ss[s], 16, 64); ss[s] += __shfl_xor(ss[s], 32, 64);
        qq[s] += __shfl_xor(qq[s], 16, 64); qq[s] += __shfl_xor(qq[s], 32, 64);
        if (lane < 16){
            pS[(size_t)(ccBase + s*64 + w*16 + lane)*512 + b] = ss[s];
            pQ[(size_t)(ccBase + s*64 + w*16 + lane)*512 + b] = qq[s];
        }
    }
    for (int i = t; i < 64*NCOL; i += 256){
        int colL = i % NCOL, j = i / NCOL;
        outenc[((size_t)b*64 + j)*COUT + ccBase + colL] = maxtab[colL*64 + (j ^ (colL & 31))];
    }
}

// ---------------- finalize edge_conv ----------------
__global__ void k_final_ec(unsigned* __restrict__ buf, const float* __restrict__ cA,
                           const float* __restrict__ cB, const float* __restrict__ g,
                           int C, int total){
    int i = blockIdx.x*256 + threadIdx.x;
    if (i >= total) return;
    int c = i & (C-1);
    unsigned e = buf[i];
    float r;
    if (e == ENC_NEGINF) r = 0.0f;
    else {
        float s = (g[c] < 0.0f) ? -1.0f : 1.0f;
        float v = s*decf(e);
        r = lrelu(cA[c]*v + cB[c]);
    }
    ((float*)buf)[i] = r;
}

// ---------------- pooling ----------------
__global__ void k_pool(const float* __restrict__ h1, const float* __restrict__ h2,
                       const float* __restrict__ h3, float* __restrict__ pooled){
    int t = threadIdx.x, b = blockIdx.x;
    for (int c = t; c < 448; c += 256){
        const float* src; int C, cl;
        if (c < 64){ src = h1; C = 64;  cl = c; }
        else if (c < 192){ src = h2; C = 128; cl = c - 64; }
        else { src = h3; C = 256; cl = c - 192; }
        const float* p = src + (size_t)b*64*C + cl;
        float s = 0.f, mx = -INFINITY;
        for (int n = 0; n < 64; n++){
            float v = p[(size_t)n*C];
            s += v; mx = fmaxf(mx, v);
        }
        pooled[b*896 + c] = s*(1.0f/64.0f);
        pooled[b*896 + 448 + c] = mx;
    }
}

// ---------------- classifier ----------------
__global__ void k_fc1(const float* __restrict__ pooled, const float* __restrict__ w,
                      float* __restrict__ z, float* gs, float* gq){
    int r = blockIdx.x;
    int co = blockIdx.y*256 + threadIdx.x;
    const float* pr = pooled + r*896;
    float acc = 0.f;
    for (int k = 0; k < 896; k++) acc += pr[k]*w[(size_t)k*512 + co];
    z[(size_t)r*512 + co] = acc;
    atomicAdd(&gs[co], acc);
    atomicAdd(&gq[co], acc*acc);
}

__global__ void k_fc2(const float* __restrict__ z1, const float* __restrict__ cA,
                      const float* __restrict__ cB, const float* __restrict__ w,
                      float* __restrict__ z2, float* gs, float* gq){
    int r = blockIdx.x;
    int co = threadIdx.x;
    const float* zr = z1 + (size_t)r*512;
    float acc = 0.f;
    for (int k = 0; k < 512; k++){
        float v = lrelu(cA[k]*zr[k] + cB[k]);
        acc += v*w[(size_t)k*256 + co];
    }
    z2[(size_t)r*256 + co] = acc;
    atomicAdd(&gs[co], acc);
    atomicAdd(&gq[co], acc*acc);
}

__global__ void k_fc3(const float* __restrict__ z2, const float* __restrict__ cA,
                      const float* __restrict__ cB, const float* __restrict__ w,
                      const float* __restrict__ bias, float* __restrict__ out){
    int r = blockIdx.x*256 + threadIdx.x;
    const float* zr = z2 + (size_t)r*256;
    float a0 = 0.f, a1 = 0.f;
    for (int k = 0; k < 256; k++){
        float v = lrelu(cA[k]*zr[k] + cB[k]);
        a0 += v*w[k*2 + 0];
        a1 += v*w[k*2 + 1];
    }
    out[r*2 + 0] = a0 + bias[0];
    out[r*2 + 1] = a1 + bias[1];
}

extern "C" void kernel_launch(void* const* d_in, const int* in_sizes, int n_in,
                              void* d_out, int out_size, void* d_ws, size_t ws_size,
                              hipStream_t stream){
    const float* x    = (const float*)d_in[0];
    const float* w_in = (const float*)d_in[2];
    const float* g_in = (const float*)d_in[3];
    const float* b_in = (const float*)d_in[4];
    const float* w1a  = (const float*)d_in[5];
    const float* g1a  = (const float*)d_in[6];
    const float* b1a  = (const float*)d_in[7];
    const float* w1b  = (const float*)d_in[8];
    const float* g1b  = (const float*)d_in[9];
    const float* b1b  = (const float*)d_in[10];
    const float* w2a  = (const float*)d_in[11];
    const float* g2a  = (const float*)d_in[12];
    const float* b2a  = (const float*)d_in[13];
    const float* w2b  = (const float*)d_in[14];
    const float* g2b  = (const float*)d_in[15];
    const float* b2b  = (const float*)d_in[16];
    const float* w3a  = (const float*)d_in[17];
    const float* g3a  = (const float*)d_in[18];
    const float* b3a  = (const float*)d_in[19];
    const float* w3b  = (const float*)d_in[20];
    const float* g3b  = (const float*)d_in[21];
    const float* b3b  = (const float*)d_in[22];
    const float* wc1  = (const float*)d_in[23];
    const float* gc1  = (const float*)d_in[24];
    const float* bc1  = (const float*)d_in[25];
    const float* wc2  = (const float*)d_in[26];
    const float* gc2  = (const float*)d_in[27];
    const float* bc2  = (const float*)d_in[28];
    const float* wc3  = (const float*)d_in[29];
    const float* bc3  = (const float*)d_in[30];

    char* ws = (char*)d_ws;
    size_t off = 0;
    auto alloc = [&](size_t bytes){
        size_t o = off; off = (off + bytes + 255) & ~(size_t)255; return o;
    };
    float* h0     = (float*)(ws + alloc((size_t)NPTS*64*4));
    float* h1     = (float*)(ws + alloc((size_t)NPTS*64*4));
    float* h2     = (float*)(ws + alloc((size_t)NPTS*128*4));
    float* h3     = (float*)(ws + alloc((size_t)NPTS*256*4));
    float* P      = (float*)(ws + alloc((size_t)NPTS*256*4));
    float* Q      = (float*)(ws + alloc((size_t)NPTS*256*4));
    int*   idx    = (int*)  (ws + alloc((size_t)NPTS*16*4));
    float* pooled = (float*)(ws + alloc((size_t)512*896*4));
    float* z1     = (float*)(ws + alloc((size_t)512*512*4));
    float* z2     = (float*)(ws + alloc((size_t)512*256*4));
    float* pS     = (float*)(ws + alloc((size_t)131072*4));
    float* pQ     = (float*)(ws + alloc((size_t)131072*4));
    float* stats  = (float*)(ws + alloc((size_t)2048*4));
    float* coefs  = (float*)(ws + alloc((size_t)3456*4));
    _Float16* wsp = (_Float16*)(ws + alloc((size_t)114688*2));

    _Float16 *w1bh = wsp,          *w1bm = wsp+4096,
             *w1dh = wsp+8192,     *w1dm = wsp+12288;           // stage1 64x64
    _Float16 *w2bh = wsp+16384,    *w2bm = wsp+24576,
             *w2dh = wsp+32768,    *w2dm = wsp+40960;           // stage2 64x128
    _Float16 *w3bh = wsp+49152,    *w3dh = wsp+81920;           // stage3 128x256

    float *f1s  = stats,       *f1q  = stats+512;
    float *f2s  = stats+1024,  *f2q  = stats+1280;
    float *cA0   = coefs,      *cB0   = coefs+64;
    float *cA1a  = coefs+128,  *cB1a  = coefs+192;
    float *cA1b  = coefs+256,  *cB1b  = coefs+320;
    float *cA2a  = coefs+384,  *cB2a  = coefs+512;
    float *cA2b  = coefs+640,  *cB2b  = coefs+768;
    float *cA3a  = coefs+896,  *cB3a  = coefs+1152;
    float *cA3b  = coefs+1408, *cB3b  = coefs+1664;
    float *cAf1  = coefs+1920, *cBf1  = coefs+2432;
    float *cAf2  = coefs+2944, *cBf2  = coefs+3200;

    (void)hipMemsetAsync(stats, 0, 2048*4, stream);

    // -------- weight prep (tiny, once per launch) --------
    k_wprep<64,64,true><<<16, 256, 0, stream>>>(w1a, w1bh, w1bm, w1dh, w1dm);
    k_wprep<64,128,true><<<32, 256, 0, stream>>>(w2a, w2bh, w2bm, w2dh, w2dm);
    k_wprep<128,256,false><<<128, 256, 0, stream>>>(w3a, w3bh, nullptr, w3dh, nullptr);

    // -------- input MLP --------
    k_input<<<NPTS/256, 256, 0, stream>>>(x, w_in, h0);
    k_colstats_part<<<64, 256, 0, stream>>>(h0, pS, pQ);
    k_bnfin_part<<<1, 64, 0, stream>>>(pS, pQ, g_in, b_in, cA0, cB0, 256, 1.0f/NPTS);
    k_apply<<<(NPTS*64)/256, 256, 0, stream>>>(h0, cA0, cB0, 64, NPTS*64);

    // -------- edge conv 1 (64 -> 64/64) --------
    k_knn<64><<<BB, 256, 0, stream>>>(h0, idx);
    k_mm1x<64,64><<<BB, 256, 0, stream>>>(h0, w1bh, w1bm, w1dh, w1dm, P, Q);
    k_stats1p<64><<<BB, 256, 0, stream>>>(P, Q, idx, pS, pQ);
    k_bnfin_part<<<1, 64, 0, stream>>>(pS, pQ, g1a, b1a, cA1a, cB1a, 2048, 1.0f/NEDGE);
    k_mm2s<64,64,1><<<dim3(BB,1), 256, 0, stream>>>(P, Q, idx, cA1a, cB1a, w1b, g1b,
                                                    (unsigned*)h1, pS, pQ);
    k_bnfin_part<<<1, 64, 0, stream>>>(pS, pQ, g1b, b1b, cA1b, cB1b, 512, 1.0f/NEDGE);
    k_final_ec<<<(NPTS*64)/256, 256, 0, stream>>>((unsigned*)h1, cA1b, cB1b, g1b, 64, NPTS*64);

    // -------- edge conv 2 (64 -> 128/128) --------
    k_knn<64><<<BB, 256, 0, stream>>>(h1, idx);
    k_mm1x<64,128><<<BB, 256, 0, stream>>>(h1, w2bh, w2bm, w2dh, w2dm, P, Q);
    k_stats1p<128><<<BB, 256, 0, stream>>>(P, Q, idx, pS, pQ);
    k_bnfin_part<<<1, 128, 0, stream>>>(pS, pQ, g2a, b2a, cA2a, cB2a, 1024, 1.0f/NEDGE);
    k_mm2s<128,128,2><<<dim3(BB,1), 256, 0, stream>>>(P, Q, idx, cA2a, cB2a, w2b, g2b,
                                                      (unsigned*)h2, pS, pQ);
    k_bnfin_part<<<1, 128, 0, stream>>>(pS, pQ, g2b, b2b, cA2b, cB2b, 512, 1.0f/NEDGE);
    k_final_ec<<<(NPTS*128)/256, 256, 0, stream>>>((unsigned*)h2, cA2b, cB2b, g2b, 128, NPTS*128);

    // -------- edge conv 3 (128 -> 256/256), f16 path (no knn downstream) -------
    k_knn<128><<<BB, 256, 0, stream>>>(h2, idx);
    k_mm1xh<128,256><<<BB, 256, 0, stream>>>(h2, w3bh, w3dh, (_Float16*)P, (_Float16*)Q);
    k_stats1h<<<BB, 256, 0, stream>>>((_Float16*)P, (_Float16*)Q, idx, pS, pQ);
    k_bnfin_part<<<1, 256, 0, stream>>>(pS, pQ, g3a, b3a, cA3a, cB3a, 512, 1.0f/NEDGE);
    k_pqfold<<<(NPTS*256)/(256*8), 256, 0, stream>>>((_Float16*)P, (_Float16*)Q, cA3a, cB3a);
    k_mm2xh<256,256,2><<<dim3(BB,2), 256, 0, stream>>>((_Float16*)P, (_Float16*)Q, idx,
                                                       w3b, g3b, (unsigned*)h3, pS, pQ);
    k_bnfin_part<<<1, 256, 0, stream>>>(pS, pQ, g3b, b3b, cA3b, cB3b, 512, 1.0f/NEDGE);
    k_final_ec<<<(NPTS*256)/256, 256, 0, stream>>>((unsigned*)h3, cA3b, cB3b, g3b, 256, NPTS*256);

    // -------- classifier --------
    k_pool<<<BB, 256, 0, stream>>>(h1, h2, h3, pooled);
    k_fc1<<<dim3(512,2), 256, 0, stream>>>(pooled, wc1, z1, f1s, f1q);
    k_bnfin<<<2, 256, 0, stream>>>(f1s, f1q, gc1, bc1, cAf1, cBf1, 512, 1.0f/512);
    k_fc2<<<512, 256, 0, stream>>>(z1, cAf1, cBf1, wc2, z2, f2s, f2q);
    k_bnfin<<<1, 256, 0, stream>>>(f2s, f2q, gc2, bc2, cAf2, cBf2, 256, 1.0f/512);
    k_fc3<<<2, 256, 0, stream>>>(z2, cAf2, cBf2, wc3, bc3, (float*)d_out);

    (void)in_sizes; (void)n_in; (void)out_size; (void)ws_size;
}

// Round 15
// 1232.736 us; speedup vs baseline: 1.1834x; 1.1834x over previous
//
#include <hip/hip_runtime.h>
#include <hip/hip_fp16.h>
#include <math.h>

#define BB 512
#define NN 64
#define KNB 16
#define NPTS (BB*NN)        // 32768
#define NEDGE (BB*NN*KNB)   // 524288
#define EPSV 1e-5f

typedef __attribute__((ext_vector_type(8))) _Float16 f16x8;
typedef __attribute__((ext_vector_type(4))) _Float16 f16x4;
typedef __attribute__((ext_vector_type(4))) float f32x4;

__device__ __forceinline__ float lrelu(float x){ return x > 0.0f ? x : 0.2f*x; }
__device__ __forceinline__ unsigned encf(float f){
    unsigned u = __float_as_uint(f);
    return (u & 0x80000000u) ? ~u : (u | 0x80000000u);
}
__device__ __forceinline__ float decf(unsigned e){
    unsigned u = (e & 0x80000000u) ? (e ^ 0x80000000u) : ~e;
    return __uint_as_float(u);
}
#define ENC_NEGINF 0x007FFFFFu   // encf(-inf)

// scaled 2-plane f16 split: v = h + (m/2048); both planes normal-range f16.
__device__ __forceinline__ void split2h(float v, _Float16& h, _Float16& m){
    h = (_Float16)v;
    float r = v - (float)h;
    m = (_Float16)(r * 2048.0f);
}

// ---------------- input MLP ----------------
__global__ void k_input(const float* __restrict__ x, const float* __restrict__ w,
                        float* __restrict__ h0){
    __shared__ float wls[6*64];
    int t = threadIdx.x;
    for (int i = t; i < 6*64; i += 256) wls[i] = w[i];
    __syncthreads();
    int row = blockIdx.x*256 + t;
    float xv[6];
#pragma unroll
    for (int k = 0; k < 6; k++) xv[k] = x[row*6 + k];
#pragma unroll 8
    for (int c = 0; c < 64; c++){
        float acc = 0.f;
#pragma unroll
        for (int k = 0; k < 6; k++) acc += xv[k]*wls[k*64 + c];
        h0[(size_t)row*64 + c] = acc;
    }
}

// ---- column stats, deterministic partials ----
__global__ void k_colstats_part(const float* __restrict__ h,
                                float* __restrict__ pS, float* __restrict__ pQ){
    int t = threadIdx.x;
    int c = t & 63;
    int g = t >> 6;
    int p = blockIdx.x*4 + g;
    const int rpb = NPTS/256;
    int r0 = p*rpb;
    float s = 0.f, q = 0.f;
    for (int r = r0; r < r0 + rpb; r++){
        float v = h[(size_t)r*64 + c];
        s += v; q += v*v;
    }
    pS[c*256 + p] = s;
    pQ[c*256 + p] = q;
}

// ---- BN finalize from partials (deterministic serial reduce) ----
__global__ void k_bnfin_part(const float* __restrict__ pS, const float* __restrict__ pQ,
                             const float* __restrict__ g, const float* __restrict__ b,
                             float* __restrict__ cA, float* __restrict__ cB,
                             int P, float invM){
    int c = threadIdx.x;
    const float* ps = pS + (size_t)c*P;
    const float* pq = pQ + (size_t)c*P;
    float s = 0.f, q = 0.f;
    for (int p = 0; p < P; p += 4){
        float4 vs = *(const float4*)(ps + p);
        float4 vq = *(const float4*)(pq + p);
        s += vs.x + vs.y + vs.z + vs.w;
        q += vq.x + vq.y + vq.z + vq.w;
    }
    float m = s*invM;
    float v = q*invM - m*m;
    v = v < 0.f ? 0.f : v;
    float a = g[c]*rsqrtf(v + EPSV);
    cA[c] = a;
    cB[c] = b[c] - m*a;
}

// ---------------- BN finalize from atomic sums (classifier only) ----------------
__global__ void k_bnfin(const float* gs, const float* gq, const float* g,
                        const float* b, float* cA, float* cB, int C, float invM){
    int c = blockIdx.x*blockDim.x + threadIdx.x;
    if (c < C){
        float m = gs[c]*invM;
        float v = gq[c]*invM - m*m;
        v = v < 0.f ? 0.f : v;
        float a = g[c]*rsqrtf(v + EPSV);
        cA[c] = a;
        cB[c] = b[c] - m*a;
    }
}

// ---------------- in-place bn+lrelu apply ----------------
__global__ void k_apply(float* h, const float* __restrict__ cA,
                        const float* __restrict__ cB, int C, int total){
    int i = blockIdx.x*256 + threadIdx.x;
    if (i < total){
        int c = i & (C-1);
        h[i] = lrelu(cA[c]*h[i] + cB[c]);
    }
}

// ---------------- knn: ILP-blocked distances + bitonic-sort selection ----------
template<int C>
__global__ void k_knn(const float* __restrict__ x, int* __restrict__ idxg){
    const int CP = C + 4;
    __shared__ __align__(16) float xls[64*CP];
    __shared__ float sq[64];
    __shared__ __align__(16) float dls[64*64];
    int t = threadIdx.x, b = blockIdx.x;
    const float* xb = x + (size_t)b*64*C;
    for (int i = t; i < 64*C; i += 256){
        int n = i / C, c = i & (C-1);
        xls[n*CP + c] = xb[i];
    }
    __syncthreads();
    if (t < 64){
        float s = 0.f;
        for (int c = 0; c < C; c += 4){
            float4 v = *(const float4*)&xls[t*CP + c];
            s += v.x*v.x + v.y*v.y + v.z*v.z + v.w*v.w;
        }
        sq[t] = s;
    }
    __syncthreads();
    {
        int n  = t >> 2;
        int m0 = (t & 3)*16;
        float acc[16];
#pragma unroll
        for (int i = 0; i < 16; i++) acc[i] = 0.f;
        const float* an = &xls[n*CP];
        const float* bm = &xls[m0*CP];
        for (int c = 0; c < C; c += 4){
            float4 a = *(const float4*)(an + c);
#pragma unroll
            for (int i = 0; i < 16; i++){
                float4 bv = *(const float4*)(bm + i*CP + c);
                acc[i] += a.x*bv.x + a.y*bv.y + a.z*bv.z + a.w*bv.w;
            }
        }
        float sn = sq[n];
#pragma unroll
        for (int i4 = 0; i4 < 16; i4 += 4){
            float4 dv;
            dv.x = sn - 2.0f*acc[i4+0] + sq[m0+i4+0];
            dv.y = sn - 2.0f*acc[i4+1] + sq[m0+i4+1];
            dv.z = sn - 2.0f*acc[i4+2] + sq[m0+i4+2];
            dv.w = sn - 2.0f*acc[i4+3] + sq[m0+i4+3];
            *(float4*)&dls[n*64 + m0 + i4] = dv;
        }
    }
    __syncthreads();
    int lane = t & 63, w = t >> 6;
    for (int pr = 0; pr < 16; pr += 4){
        int n0 = w*16 + pr;
        unsigned long long c0 = (((unsigned long long)encf(dls[(n0+0)*64 + lane])) << 32) | (unsigned)lane;
        unsigned long long c1 = (((unsigned long long)encf(dls[(n0+1)*64 + lane])) << 32) | (unsigned)lane;
        unsigned long long c2 = (((unsigned long long)encf(dls[(n0+2)*64 + lane])) << 32) | (unsigned)lane;
        unsigned long long c3 = (((unsigned long long)encf(dls[(n0+3)*64 + lane])) << 32) | (unsigned)lane;
#pragma unroll
        for (int k = 2; k <= 64; k <<= 1){
#pragma unroll
            for (int j = k >> 1; j > 0; j >>= 1){
                bool keepmin = ((lane & j) == 0) == ((lane & k) == 0);
                unsigned long long o0 = __shfl_xor(c0, j, 64);
                unsigned long long o1 = __shfl_xor(c1, j, 64);
                unsigned long long o2 = __shfl_xor(c2, j, 64);
                unsigned long long o3 = __shfl_xor(c3, j, 64);
                c0 = keepmin ? (c0 < o0 ? c0 : o0) : (c0 < o0 ? o0 : c0);
                c1 = keepmin ? (c1 < o1 ? c1 : o1) : (c1 < o1 ? o1 : c1);
                c2 = keepmin ? (c2 < o2 ? c2 : o2) : (c2 < o2 ? o2 : c2);
                c3 = keepmin ? (c3 < o3 ? c3 : o3) : (c3 < o3 ? o3 : c3);
            }
        }
        if (lane >= 1 && lane <= KNB){
            int base = b*1024 + n0*16 + lane - 1;
            idxg[base]      = (int)(c0 & 0xffffffffu);
            idxg[base + 16] = (int)(c1 & 0xffffffffu);
            idxg[base + 32] = (int)(c2 & 0xffffffffu);
            idxg[base + 48] = (int)(c3 & 0xffffffffu);
        }
    }
}

// ---- weight prep: wb = w1[CIN+k][c], wd = w1[k][c]-wb -> transposed f16 planes
template<int CIN, int CMID, bool SPLIT>
__global__ void k_wprep(const float* __restrict__ w1,
                        _Float16* __restrict__ wbh, _Float16* __restrict__ wbm,
                        _Float16* __restrict__ wdh, _Float16* __restrict__ wdm){
    int i = blockIdx.x*256 + threadIdx.x;
    if (i >= CIN*CMID) return;
    int k = i / CMID, c = i - k*CMID;
    float wb = w1[(size_t)(CIN + k)*CMID + c];
    float wd = w1[(size_t)k*CMID + c] - wb;
    size_t o = (size_t)c*CIN + k;
    if (SPLIT){
        _Float16 h, m;
        split2h(wb, h, m); wbh[o] = h; wbm[o] = m;
        split2h(wd, h, m); wdh[o] = h; wdm[o] = m;
    } else {
        wbh[o] = (_Float16)wb;
        wdh[o] = (_Float16)wd;
    }
}

// ---- mm1x: P = x@wb, Q = x@wd via split2h f16 MFMA (stages 1,2; f32 out) ----
template<int CIN, int CMID>
__global__ __launch_bounds__(256)
void k_mm1x(const float* __restrict__ x,
            const _Float16* __restrict__ wbh, const _Float16* __restrict__ wbm,
            const _Float16* __restrict__ wdh, const _Float16* __restrict__ wdm,
            float* __restrict__ P, float* __restrict__ Q){
    int t = threadIdx.x, b = blockIdx.x;
    int lane = t & 63, w = t >> 6;
    int lrow = lane & 15, lk = lane >> 4;
    const int KT = CIN/32;
    f16x8 ah[KT], am[KT];
    {
        const float* xr = x + ((size_t)b*64 + w*16 + lrow)*CIN;
#pragma unroll
        for (int kt = 0; kt < KT; kt++){
            union { f16x8 v; _Float16 u[8]; } H, M;
#pragma unroll
            for (int j = 0; j < 8; j++)
                split2h(xr[kt*32 + lk*8 + j], H.u[j], M.u[j]);
            ah[kt] = H.v; am[kt] = M.v;
        }
    }
#pragma unroll
    for (int ct = 0; ct < CMID/16; ct++){
        int col = ct*16 + lrow;
        f32x4 aPM = {0,0,0,0}, aPC = {0,0,0,0};
        f32x4 aQM = {0,0,0,0}, aQC = {0,0,0,0};
#pragma unroll
        for (int kt = 0; kt < KT; kt++){
            size_t bo = (size_t)col*CIN + kt*32 + lk*8;
            f16x8 bbh = *(const f16x8*)(wbh + bo);
            f16x8 bbm = *(const f16x8*)(wbm + bo);
            f16x8 bdh = *(const f16x8*)(wdh + bo);
            f16x8 bdm = *(const f16x8*)(wdm + bo);
            aPM = __builtin_amdgcn_mfma_f32_16x16x32_f16(ah[kt], bbh, aPM, 0, 0, 0);
            aPC = __builtin_amdgcn_mfma_f32_16x16x32_f16(ah[kt], bbm, aPC, 0, 0, 0);
            aPC = __builtin_amdgcn_mfma_f32_16x16x32_f16(am[kt], bbh, aPC, 0, 0, 0);
            aQM = __builtin_amdgcn_mfma_f32_16x16x32_f16(ah[kt], bdh, aQM, 0, 0, 0);
            aQC = __builtin_amdgcn_mfma_f32_16x16x32_f16(ah[kt], bdm, aQC, 0, 0, 0);
            aQC = __builtin_amdgcn_mfma_f32_16x16x32_f16(am[kt], bdh, aQC, 0, 0, 0);
        }
#pragma unroll
        for (int u = 0; u < 4; u++){
            size_t o = ((size_t)b*64 + w*16 + lk*4 + u)*CMID + col;
            P[o] = aPM[u] + aPC[u]*(1.0f/2048.0f);
            Q[o] = aQM[u] + aQC[u]*(1.0f/2048.0f);
        }
    }
}

// ---- mm1xh: stage 3, plain f16 MFMA, f16 outputs ----
template<int CIN, int CMID>
__global__ __launch_bounds__(256)
void k_mm1xh(const float* __restrict__ x,
             const _Float16* __restrict__ wbh, const _Float16* __restrict__ wdh,
             _Float16* __restrict__ P, _Float16* __restrict__ Q){
    int t = threadIdx.x, b = blockIdx.x;
    int lane = t & 63, w = t >> 6;
    int lrow = lane & 15, lk = lane >> 4;
    const int KT = CIN/32;
    f16x8 ah[KT];
    {
        const float* xr = x + ((size_t)b*64 + w*16 + lrow)*CIN;
#pragma unroll
        for (int kt = 0; kt < KT; kt++){
            union { f16x8 v; _Float16 u[8]; } H;
#pragma unroll
            for (int j = 0; j < 8; j++)
                H.u[j] = (_Float16)xr[kt*32 + lk*8 + j];
            ah[kt] = H.v;
        }
    }
#pragma unroll
    for (int ct = 0; ct < CMID/16; ct++){
        int col = ct*16 + lrow;
        f32x4 aP = {0,0,0,0}, aQ = {0,0,0,0};
#pragma unroll
        for (int kt = 0; kt < KT; kt++){
            size_t bo = (size_t)col*CIN + kt*32 + lk*8;
            f16x8 bbh = *(const f16x8*)(wbh + bo);
            f16x8 bdh = *(const f16x8*)(wdh + bo);
            aP = __builtin_amdgcn_mfma_f32_16x16x32_f16(ah[kt], bbh, aP, 0, 0, 0);
            aQ = __builtin_amdgcn_mfma_f32_16x16x32_f16(ah[kt], bdh, aQ, 0, 0, 0);
        }
#pragma unroll
        for (int u = 0; u < 4; u++){
            size_t o = ((size_t)b*64 + w*16 + lk*4 + u)*CMID + col;
            P[o] = (_Float16)aP[u];
            Q[o] = (_Float16)aQ[u];
        }
    }
}

// ---- stats over per-edge h = P[n]+Q[idx], f32 inputs (stages 1,2) ----
template<int CMID>
__global__ void k_stats1p(const float* __restrict__ P, const float* __restrict__ Q,
                          const int* __restrict__ idxg,
                          float* __restrict__ pS, float* __restrict__ pQ){
    int t = threadIdx.x, b = blockIdx.x;
    const int NG = 256/CMID;
    const int PT = 512*NG;
    int c = t & (CMID-1);
    int g = t / CMID;
    int epg = 1024/NG;
    const float* Pb = P + (size_t)b*64*CMID;
    const float* Qb = Q + (size_t)b*64*CMID;
    const int* ib = idxg + b*1024;
    float s = 0.f, q = 0.f;
    for (int e = g*epg; e < (g+1)*epg; e++){
        int n = e >> 4;
        int j = ib[e];
        float v = Pb[n*CMID + c] + Qb[j*CMID + c];
        s += v; q += v*v;
    }
    int p = b*NG + g;
    pS[(size_t)c*PT + p] = s;
    pQ[(size_t)c*PT + p] = q;
}

// ---- stats1h: f16 inputs, P-row hoisted (stage 3); fixed summation order ----
__global__ void k_stats1h(const _Float16* __restrict__ P, const _Float16* __restrict__ Q,
                          const int* __restrict__ idxg,
                          float* __restrict__ pS, float* __restrict__ pQ){
    __shared__ int ils[1024];
    int t = threadIdx.x, b = blockIdx.x;
    for (int i = t; i < 1024; i += 256) ils[i] = idxg[b*1024 + i];
    __syncthreads();
    const _Float16* Pb = P + (size_t)b*64*256;
    const _Float16* Qb = Q + (size_t)b*64*256;
    float s = 0.f, q = 0.f;
    for (int n = 0; n < 64; n++){
        float p = (float)Pb[n*256 + t];
#pragma unroll 4
        for (int k = 0; k < 16; k++){
            int j = ils[n*16 + k];
            float v = p + (float)Qb[j*256 + t];
            s += v; q += v*v;
        }
    }
    pS[(size_t)t*512 + b] = s;
    pQ[(size_t)t*512 + b] = q;
}

// ---------------- mm2s: scaled 2-plane f16 MFMA (stages 1,2 — feed knn) --------
template<int CMID, int COUT, int NSET>
__global__ __launch_bounds__(256)
void k_mm2s(const float* __restrict__ P, const float* __restrict__ Q,
            const int* __restrict__ idxg,
            const float* __restrict__ cA1, const float* __restrict__ cB1,
            const float* __restrict__ w2, const float* __restrict__ g2,
            unsigned* __restrict__ outenc,
            float* __restrict__ pS, float* __restrict__ pQ){
    const int AS = CMID + 8;
    const int NCOL = 64*NSET;
    __shared__ __align__(16) _Float16 act_h[32*AS];
    __shared__ __align__(16) _Float16 act_m[32*AS];
    __shared__ unsigned maxtab[NCOL*65];
    __shared__ int ils[1024];
    __shared__ __align__(16) float a1ls[CMID];
    __shared__ __align__(16) float b1ls[CMID];
    int t = threadIdx.x, b = blockIdx.x, cc = blockIdx.y;
    int lane = t & 63, w = t >> 6;
    int lrow = lane & 15, lk = lane >> 4;

    for (int i = t; i < 1024; i += 256) ils[i] = idxg[b*1024 + i];
    for (int i = t; i < CMID; i += 256){ a1ls[i] = cA1[i]; b1ls[i] = cB1[i]; }
    for (int i = t; i < NCOL*65; i += 256) maxtab[i] = ENC_NEGINF;

    const int KT = CMID/32;
    f16x8 bh[NSET][KT], bm[NSET][KT];
    float sg[NSET];
    int ccBase = cc*NCOL;
#pragma unroll
    for (int s = 0; s < NSET; s++){
        int ncol = ccBase + s*64 + w*16 + lrow;
#pragma unroll
        for (int kt = 0; kt < KT; kt++){
            union { f16x8 v; _Float16 u[8]; } uh, um;
#pragma unroll
            for (int j = 0; j < 8; j++){
                int k = kt*32 + lk*8 + j;
                split2h(w2[(size_t)k*COUT + ncol], uh.u[j], um.u[j]);
            }
            bh[s][kt] = uh.v; bm[s][kt] = um.v;
        }
        sg[s] = (g2[ncol] < 0.0f) ? -1.0f : 1.0f;
    }
    float ss[NSET], qq[NSET];
#pragma unroll
    for (int s = 0; s < NSET; s++){ ss[s] = 0.f; qq[s] = 0.f; }
    const float* Pb = P + (size_t)b*64*CMID;
    const float* Qb = Q + (size_t)b*64*CMID;
    __syncthreads();

    for (int ch = 0; ch < 32; ch++){
        for (int i = t*4; i < 32*CMID; i += 1024){
            int le = i / CMID, k = i & (CMID-1);
            int e = ch*32 + le;
            int n = e >> 4, j = ils[e];
            float4 pv = *(const float4*)(Pb + n*CMID + k);
            float4 qv = *(const float4*)(Qb + j*CMID + k);
            float4 ca = *(const float4*)&a1ls[k];
            float4 cb = *(const float4*)&b1ls[k];
            float v0 = lrelu(ca.x*(pv.x + qv.x) + cb.x);
            float v1 = lrelu(ca.y*(pv.y + qv.y) + cb.y);
            float v2 = lrelu(ca.z*(pv.z + qv.z) + cb.z);
            float v3 = lrelu(ca.w*(pv.w + qv.w) + cb.w);
            union { f16x4 v; _Float16 u[4]; } hh, mm;
            split2h(v0, hh.u[0], mm.u[0]);
            split2h(v1, hh.u[1], mm.u[1]);
            split2h(v2, hh.u[2], mm.u[2]);
            split2h(v3, hh.u[3], mm.u[3]);
            *(f16x4*)&act_h[le*AS + k] = hh.v;
            *(f16x4*)&act_m[le*AS + k] = mm.v;
        }
        __syncthreads();

        f32x4 accM[2][NSET], accC[2][NSET];
#pragma unroll
        for (int r = 0; r < 2; r++)
#pragma unroll
            for (int s = 0; s < NSET; s++){
                accM[r][s] = {0.f,0.f,0.f,0.f};
                accC[r][s] = {0.f,0.f,0.f,0.f};
            }
#pragma unroll
        for (int kt = 0; kt < KT; kt++){
            int ko = kt*32 + lk*8;
#pragma unroll
            for (int r = 0; r < 2; r++){
                f16x8 ah = *(const f16x8*)&act_h[(r*16 + lrow)*AS + ko];
                f16x8 am = *(const f16x8*)&act_m[(r*16 + lrow)*AS + ko];
#pragma unroll
                for (int s = 0; s < NSET; s++){
                    accM[r][s] = __builtin_amdgcn_mfma_f32_16x16x32_f16(ah, bh[s][kt], accM[r][s], 0, 0, 0);
                    accC[r][s] = __builtin_amdgcn_mfma_f32_16x16x32_f16(ah, bm[s][kt], accC[r][s], 0, 0, 0);
                    accC[r][s] = __builtin_amdgcn_mfma_f32_16x16x32_f16(am, bh[s][kt], accC[r][s], 0, 0, 0);
                }
            }
        }
#pragma unroll
        for (int r = 0; r < 2; r++){
#pragma unroll
            for (int s = 0; s < NSET; s++){
#pragma unroll
                for (int u = 0; u < 4; u++){
                    int e = ch*32 + r*16 + lk*4 + u;
                    float v = accM[r][s][u] + accC[r][s][u]*(1.0f/2048.0f);
                    ss[s] += v; qq[s] += v*v;
                    int colL = s*64 + w*16 + lrow;
                    atomicMax(&maxtab[colL*65 + ils[e]], encf(sg[s]*v));
                }
            }
        }
        __syncthreads();
    }
#pragma unroll
    for (int s = 0; s < NSET; s++){
        ss[s] += __shfl_xor(ss[s], 16, 64); ss[s] += __shfl_xor(ss[s], 32, 64);
        qq[s] += __shfl_xor(qq[s], 16, 64); qq[s] += __shfl_xor(qq[s], 32, 64);
        if (lane < 16){
            pS[(size_t)(ccBase + s*64 + w*16 + lane)*512 + b] = ss[s];
            pQ[(size_t)(ccBase + s*64 + w*16 + lane)*512 + b] = qq[s];
        }
    }
    for (int i = t; i < 64*NCOL; i += 256){
        int colL = i % NCOL, j = i / NCOL;
        outenc[((size_t)b*64 + j)*COUT + ccBase + colL] = maxtab[colL*65 + j];
    }
}

// ---------------- mm2xh: f16 MFMA, packed-f16 act-build (stage 3) --------------
template<int CMID, int COUT, int NSET>
__global__ __launch_bounds__(256)
void k_mm2xh(const _Float16* __restrict__ P, const _Float16* __restrict__ Q,
             const int* __restrict__ idxg,
             const float* __restrict__ cA1, const float* __restrict__ cB1,
             const float* __restrict__ w2, const float* __restrict__ g2,
             unsigned* __restrict__ outenc,
             float* __restrict__ pS, float* __restrict__ pQ){
    const int AS = CMID + 8;
    const int NCOL = 64*NSET;
    __shared__ __align__(16) _Float16 act[32*AS];
    __shared__ unsigned maxtab[NCOL*65];
    __shared__ int ils[1024];
    __shared__ __align__(16) _Float16 a1h[CMID];
    __shared__ __align__(16) _Float16 b1h[CMID];
    int t = threadIdx.x, b = blockIdx.x, cc = blockIdx.y;
    int lane = t & 63, w = t >> 6;
    int lrow = lane & 15, lk = lane >> 4;

    for (int i = t; i < 1024; i += 256) ils[i] = idxg[b*1024 + i];
    for (int i = t; i < CMID; i += 256){
        a1h[i] = (_Float16)cA1[i];
        b1h[i] = (_Float16)cB1[i];
    }
    for (int i = t; i < NCOL*65; i += 256) maxtab[i] = ENC_NEGINF;

    const int KT = CMID/32;
    f16x8 breg[NSET][KT];
    float sg[NSET];
    int ccBase = cc*NCOL;
#pragma unroll
    for (int s = 0; s < NSET; s++){
        int ncol = ccBase + s*64 + w*16 + lrow;
#pragma unroll
        for (int kt = 0; kt < KT; kt++){
            union { f16x8 v; _Float16 u[8]; } bu;
#pragma unroll
            for (int j = 0; j < 8; j++){
                int k = kt*32 + lk*8 + j;
                bu.u[j] = (_Float16)w2[(size_t)k*COUT + ncol];
            }
            breg[s][kt] = bu.v;
        }
        sg[s] = (g2[ncol] < 0.0f) ? -1.0f : 1.0f;
    }
    float ss[NSET], qq[NSET];
#pragma unroll
    for (int s = 0; s < NSET; s++){ ss[s] = 0.f; qq[s] = 0.f; }
    const _Float16* Pb = P + (size_t)b*64*CMID;
    const _Float16* Qb = Q + (size_t)b*64*CMID;
    __syncthreads();

    for (int ch = 0; ch < 32; ch++){
        for (int i = t*8; i < 32*CMID; i += 2048){
            int le = i / CMID, k = i & (CMID-1);
            int e = ch*32 + le;
            int n = e >> 4, j = ils[e];
            f16x8 pv = *(const f16x8*)(Pb + (size_t)n*CMID + k);
            f16x8 qv = *(const f16x8*)(Qb + (size_t)j*CMID + k);
            f16x8 ca = *(const f16x8*)&a1h[k];
            f16x8 cb = *(const f16x8*)&b1h[k];
            f16x8 v = ca*(pv + qv) + cb;
            f16x8 vm = v * (_Float16)0.2f;
            union { f16x8 x; _Float16 e8[8]; } V, M, R;
            V.x = v; M.x = vm;
#pragma unroll
            for (int u = 0; u < 8; u++)
                R.e8[u] = (V.e8[u] > (_Float16)0.0f) ? V.e8[u] : M.e8[u];
            *(f16x8*)&act[le*AS + k] = R.x;
        }
        __syncthreads();

        f32x4 acc[2][NSET];
#pragma unroll
        for (int r = 0; r < 2; r++)
#pragma unroll
            for (int s = 0; s < NSET; s++) acc[r][s] = {0.f,0.f,0.f,0.f};
#pragma unroll
        for (int kt = 0; kt < KT; kt++){
            int ko = kt*32 + lk*8;
#pragma unroll
            for (int r = 0; r < 2; r++){
                f16x8 a = *(const f16x8*)&act[(r*16 + lrow)*AS + ko];
#pragma unroll
                for (int s = 0; s < NSET; s++)
                    acc[r][s] = __builtin_amdgcn_mfma_f32_16x16x32_f16(a, breg[s][kt], acc[r][s], 0, 0, 0);
            }
        }
#pragma unroll
        for (int r = 0; r < 2; r++){
#pragma unroll
            for (int s = 0; s < NSET; s++){
#pragma unroll
                for (int u = 0; u < 4; u++){
                    int e = ch*32 + r*16 + lk*4 + u;
                    float v = acc[r][s][u];
                    ss[s] += v; qq[s] += v*v;
                    int colL = s*64 + w*16 + lrow;
                    atomicMax(&maxtab[colL*65 + ils[e]], encf(sg[s]*v));
                }
            }
        }
        __syncthreads();
    }
#pragma unroll
    for (int s = 0; s < NSET; s++){
        ss[s] += __shfl_xor(ss[s], 16, 64); ss[s] += __shfl_xor(ss[s], 32, 64);
        qq[s] += __shfl_xor(qq[s], 16, 64); qq[s] += __shfl_xor(qq[s], 32, 64);
        if (lane < 16){
            pS[(size_t)(ccBase + s*64 + w*16 + lane)*512 + b] = ss[s];
            pQ[(size_t)(ccBase + s*64 + w*16 + lane)*512 + b] = qq[s];
        }
    }
    for (int i = t; i < 64*NCOL; i += 256){
        int colL = i % NCOL, j = i / NCOL;
        outenc[((size_t)b*64 + j)*COUT + ccBase + colL] = maxtab[colL*65 + j];
    }
}

// ---------------- finalize edge_conv (h1/h2 only; h3 decoded in k_pool) --------
__global__ void k_final_ec(unsigned* __restrict__ buf, const float* __restrict__ cA,
                           const float* __restrict__ cB, const float* __restrict__ g,
                           int C, int total){
    int i = blockIdx.x*256 + threadIdx.x;
    if (i >= total) return;
    int c = i & (C-1);
    unsigned e = buf[i];
    float r;
    if (e == ENC_NEGINF) r = 0.0f;
    else {
        float s = (g[c] < 0.0f) ? -1.0f : 1.0f;
        float v = s*decf(e);
        r = lrelu(cA[c]*v + cB[c]);
    }
    ((float*)buf)[i] = r;
}

// ---------------- pooling: h3 decoded inline (bn3b+lrelu fused) ----------------
__global__ void k_pool(const float* __restrict__ h1, const float* __restrict__ h2,
                       const unsigned* __restrict__ h3e,
                       const float* __restrict__ cA3, const float* __restrict__ cB3,
                       const float* __restrict__ g3, float* __restrict__ pooled){
    int t = threadIdx.x, b = blockIdx.x;
    for (int c = t; c < 448; c += 256){
        float s = 0.f, mx = -INFINITY;
        if (c < 192){
            const float* src; int C, cl;
            if (c < 64){ src = h1; C = 64;  cl = c; }
            else { src = h2; C = 128; cl = c - 64; }
            const float* p = src + (size_t)b*64*C + cl;
            for (int n = 0; n < 64; n++){
                float v = p[(size_t)n*C];
                s += v; mx = fmaxf(mx, v);
            }
        } else {
            int cl = c - 192;
            float ca = cA3[cl], cb = cB3[cl];
            float sgn = (g3[cl] < 0.0f) ? -1.0f : 1.0f;
            const unsigned* p = h3e + (size_t)b*64*256 + cl;
            for (int n = 0; n < 64; n++){
                unsigned e = p[(size_t)n*256];
                float v;
                if (e == ENC_NEGINF) v = 0.0f;
                else v = lrelu(ca*(sgn*decf(e)) + cb);
                s += v; mx = fmaxf(mx, v);
            }
        }
        pooled[b*896 + c] = s*(1.0f/64.0f);
        pooled[b*896 + 448 + c] = mx;
    }
}

// ---------------- classifier ----------------
__global__ void k_fc1(const float* __restrict__ pooled, const float* __restrict__ w,
                      float* __restrict__ z, float* gs, float* gq){
    int r = blockIdx.x;
    int co = blockIdx.y*256 + threadIdx.x;
    const float* pr = pooled + r*896;
    float acc = 0.f;
    for (int k = 0; k < 896; k++) acc += pr[k]*w[(size_t)k*512 + co];
    z[(size_t)r*512 + co] = acc;
    atomicAdd(&gs[co], acc);
    atomicAdd(&gq[co], acc*acc);
}

__global__ void k_fc2(const float* __restrict__ z1, const float* __restrict__ cA,
                      const float* __restrict__ cB, const float* __restrict__ w,
                      float* __restrict__ z2, float* gs, float* gq){
    int r = blockIdx.x;
    int co = threadIdx.x;
    const float* zr = z1 + (size_t)r*512;
    float acc = 0.f;
    for (int k = 0; k < 512; k++){
        float v = lrelu(cA[k]*zr[k] + cB[k]);
        acc += v*w[(size_t)k*256 + co];
    }
    z2[(size_t)r*256 + co] = acc;
    atomicAdd(&gs[co], acc);
    atomicAdd(&gq[co], acc*acc);
}

__global__ void k_fc3(const float* __restrict__ z2, const float* __restrict__ cA,
                      const float* __restrict__ cB, const float* __restrict__ w,
                      const float* __restrict__ bias, float* __restrict__ out){
    int r = blockIdx.x*256 + threadIdx.x;
    const float* zr = z2 + (size_t)r*256;
    float a0 = 0.f, a1 = 0.f;
    for (int k = 0; k < 256; k++){
        float v = lrelu(cA[k]*zr[k] + cB[k]);
        a0 += v*w[k*2 + 0];
        a1 += v*w[k*2 + 1];
    }
    out[r*2 + 0] = a0 + bias[0];
    out[r*2 + 1] = a1 + bias[1];
}

extern "C" void kernel_launch(void* const* d_in, const int* in_sizes, int n_in,
                              void* d_out, int out_size, void* d_ws, size_t ws_size,
                              hipStream_t stream){
    const float* x    = (const float*)d_in[0];
    const float* w_in = (const float*)d_in[2];
    const float* g_in = (const float*)d_in[3];
    const float* b_in = (const float*)d_in[4];
    const float* w1a  = (const float*)d_in[5];
    const float* g1a  = (const float*)d_in[6];
    const float* b1a  = (const float*)d_in[7];
    const float* w1b  = (const float*)d_in[8];
    const float* g1b  = (const float*)d_in[9];
    const float* b1b  = (const float*)d_in[10];
    const float* w2a  = (const float*)d_in[11];
    const float* g2a  = (const float*)d_in[12];
    const float* b2a  = (const float*)d_in[13];
    const float* w2b  = (const float*)d_in[14];
    const float* g2b  = (const float*)d_in[15];
    const float* b2b  = (const float*)d_in[16];
    const float* w3a  = (const float*)d_in[17];
    const float* g3a  = (const float*)d_in[18];
    const float* b3a  = (const float*)d_in[19];
    const float* w3b  = (const float*)d_in[20];
    const float* g3b  = (const float*)d_in[21];
    const float* b3b  = (const float*)d_in[22];
    const float* wc1  = (const float*)d_in[23];
    const float* gc1  = (const float*)d_in[24];
    const float* bc1  = (const float*)d_in[25];
    const float* wc2  = (const float*)d_in[26];
    const float* gc2  = (const float*)d_in[27];
    const float* bc2  = (const float*)d_in[28];
    const float* wc3  = (const float*)d_in[29];
    const float* bc3  = (const float*)d_in[30];

    char* ws = (char*)d_ws;
    size_t off = 0;
    auto alloc = [&](size_t bytes){
        size_t o = off; off = (off + bytes + 255) & ~(size_t)255; return o;
    };
    float* h0     = (float*)(ws + alloc((size_t)NPTS*64*4));
    float* h1     = (float*)(ws + alloc((size_t)NPTS*64*4));
    float* h2     = (float*)(ws + alloc((size_t)NPTS*128*4));
    float* h3     = (float*)(ws + alloc((size_t)NPTS*256*4));
    float* P      = (float*)(ws + alloc((size_t)NPTS*256*4));
    float* Q      = (float*)(ws + alloc((size_t)NPTS*256*4));
    int*   idx    = (int*)  (ws + alloc((size_t)NPTS*16*4));
    float* pooled = (float*)(ws + alloc((size_t)512*896*4));
    float* z1     = (float*)(ws + alloc((size_t)512*512*4));
    float* z2     = (float*)(ws + alloc((size_t)512*256*4));
    float* pS     = (float*)(ws + alloc((size_t)131072*4));
    float* pQ     = (float*)(ws + alloc((size_t)131072*4));
    float* stats  = (float*)(ws + alloc((size_t)2048*4));
    float* coefs  = (float*)(ws + alloc((size_t)3456*4));
    _Float16* wsp = (_Float16*)(ws + alloc((size_t)114688*2));

    _Float16 *w1bh = wsp,          *w1bm = wsp+4096,
             *w1dh = wsp+8192,     *w1dm = wsp+12288;           // stage1 64x64
    _Float16 *w2bh = wsp+16384,    *w2bm = wsp+24576,
             *w2dh = wsp+32768,    *w2dm = wsp+40960;           // stage2 64x128
    _Float16 *w3bh = wsp+49152,    *w3dh = wsp+81920;           // stage3 128x256

    float *f1s  = stats,       *f1q  = stats+512;
    float *f2s  = stats+1024,  *f2q  = stats+1280;
    float *cA0   = coefs,      *cB0   = coefs+64;
    float *cA1a  = coefs+128,  *cB1a  = coefs+192;
    float *cA1b  = coefs+256,  *cB1b  = coefs+320;
    float *cA2a  = coefs+384,  *cB2a  = coefs+512;
    float *cA2b  = coefs+640,  *cB2b  = coefs+768;
    float *cA3a  = coefs+896,  *cB3a  = coefs+1152;
    float *cA3b  = coefs+1408, *cB3b  = coefs+1664;
    float *cAf1  = coefs+1920, *cBf1  = coefs+2432;
    float *cAf2  = coefs+2944, *cBf2  = coefs+3200;

    (void)hipMemsetAsync(stats, 0, 2048*4, stream);

    // -------- weight prep (tiny, once per launch) --------
    k_wprep<64,64,true><<<16, 256, 0, stream>>>(w1a, w1bh, w1bm, w1dh, w1dm);
    k_wprep<64,128,true><<<32, 256, 0, stream>>>(w2a, w2bh, w2bm, w2dh, w2dm);
    k_wprep<128,256,false><<<128, 256, 0, stream>>>(w3a, w3bh, nullptr, w3dh, nullptr);

    // -------- input MLP --------
    k_input<<<NPTS/256, 256, 0, stream>>>(x, w_in, h0);
    k_colstats_part<<<64, 256, 0, stream>>>(h0, pS, pQ);
    k_bnfin_part<<<1, 64, 0, stream>>>(pS, pQ, g_in, b_in, cA0, cB0, 256, 1.0f/NPTS);
    k_apply<<<(NPTS*64)/256, 256, 0, stream>>>(h0, cA0, cB0, 64, NPTS*64);

    // -------- edge conv 1 (64 -> 64/64) --------
    k_knn<64><<<BB, 256, 0, stream>>>(h0, idx);
    k_mm1x<64,64><<<BB, 256, 0, stream>>>(h0, w1bh, w1bm, w1dh, w1dm, P, Q);
    k_stats1p<64><<<BB, 256, 0, stream>>>(P, Q, idx, pS, pQ);
    k_bnfin_part<<<1, 64, 0, stream>>>(pS, pQ, g1a, b1a, cA1a, cB1a, 2048, 1.0f/NEDGE);
    k_mm2s<64,64,1><<<dim3(BB,1), 256, 0, stream>>>(P, Q, idx, cA1a, cB1a, w1b, g1b,
                                                    (unsigned*)h1, pS, pQ);
    k_bnfin_part<<<1, 64, 0, stream>>>(pS, pQ, g1b, b1b, cA1b, cB1b, 512, 1.0f/NEDGE);
    k_final_ec<<<(NPTS*64)/256, 256, 0, stream>>>((unsigned*)h1, cA1b, cB1b, g1b, 64, NPTS*64);

    // -------- edge conv 2 (64 -> 128/128) --------
    k_knn<64><<<BB, 256, 0, stream>>>(h1, idx);
    k_mm1x<64,128><<<BB, 256, 0, stream>>>(h1, w2bh, w2bm, w2dh, w2dm, P, Q);
    k_stats1p<128><<<BB, 256, 0, stream>>>(P, Q, idx, pS, pQ);
    k_bnfin_part<<<1, 128, 0, stream>>>(pS, pQ, g2a, b2a, cA2a, cB2a, 1024, 1.0f/NEDGE);
    k_mm2s<128,128,2><<<dim3(BB,1), 256, 0, stream>>>(P, Q, idx, cA2a, cB2a, w2b, g2b,
                                                      (unsigned*)h2, pS, pQ);
    k_bnfin_part<<<1, 128, 0, stream>>>(pS, pQ, g2b, b2b, cA2b, cB2b, 512, 1.0f/NEDGE);
    k_final_ec<<<(NPTS*128)/256, 256, 0, stream>>>((unsigned*)h2, cA2b, cB2b, g2b, 128, NPTS*128);

    // -------- edge conv 3 (128 -> 256/256), f16 path (no knn downstream) -------
    k_knn<128><<<BB, 256, 0, stream>>>(h2, idx);
    k_mm1xh<128,256><<<BB, 256, 0, stream>>>(h2, w3bh, w3dh, (_Float16*)P, (_Float16*)Q);
    k_stats1h<<<BB, 256, 0, stream>>>((_Float16*)P, (_Float16*)Q, idx, pS, pQ);
    k_bnfin_part<<<1, 256, 0, stream>>>(pS, pQ, g3a, b3a, cA3a, cB3a, 512, 1.0f/NEDGE);
    k_mm2xh<256,256,2><<<dim3(BB,2), 256, 0, stream>>>((_Float16*)P, (_Float16*)Q, idx,
                                                       cA3a, cB3a, w3b, g3b,
                                                       (unsigned*)h3, pS, pQ);
    k_bnfin_part<<<1, 256, 0, stream>>>(pS, pQ, g3b, b3b, cA3b, cB3b, 512, 1.0f/NEDGE);
    // h3 stays encoded; decoded inline in k_pool (saves 67 MB of traffic)

    // -------- classifier --------
    k_pool<<<BB, 256, 0, stream>>>(h1, h2, (const unsigned*)h3, cA3b, cB3b, g3b, pooled);
    k_fc1<<<dim3(512,2), 256, 0, stream>>>(pooled, wc1, z1, f1s, f1q);
    k_bnfin<<<2, 256, 0, stream>>>(f1s, f1q, gc1, bc1, cAf1, cBf1, 512, 1.0f/512);
    k_fc2<<<512, 256, 0, stream>>>(z1, cAf1, cBf1, wc2, z2, f2s, f2q);
    k_bnfin<<<1, 256, 0, stream>>>(f2s, f2q, gc2, bc2, cAf2, cBf2, 256, 1.0f/512);
    k_fc3<<<2, 256, 0, stream>>>(z2, cAf2, cBf2, wc3, bc3, (float*)d_out);

    (void)in_sizes; (void)n_in; (void)out_size; (void)ws_size;
}